// Round 1
// 119.241 us; speedup vs baseline: 1.0663x; 1.0663x over previous
//
#include <hip/hip_runtime.h>
#include <math.h>

// DirectionalContrastiveLoss — N=8, C=192, H=W=112, T=0.1
//
// R7: channel-split + bigger tile + wide LDS + packed fp32.
//  - NT=512, two channel-halves per block (ch 0..95 / 96..191); each half
//    stages/computes its channels; s[d] and norm partials combined via LDS.
//    -> 448 blocks x 8 waves = 14 waves/CU (R6: 7) at the same HBM traffic.
//  - tile 4x56 (+halo = 6x58): halo factor 2.07 -> 1.55 (HBM ~160->119 MB).
//  - LDS as float4 groups: 18 ds_read_b128 per 8-ch chunk (R6: 36 b64).
//  - v_pk_fma_f32 accumulation (s2[d] holds even/odd channel partial sums).
//  - center self-dot s[4] dropped: equals staged norm sum (read from ssp).

namespace {
constexpr int N_ = 8, C_ = 192, H_ = 112, W_ = 112;
constexpr int HW = H_ * W_;
constexpr int TH = 4;                  // pixel rows per block
constexpr int WS = 56;                 // pixel cols per block
constexpr int TROWS = TH + 2;          // 6
constexpr int TCOLS = WS + 2;          // 58
constexpr int TILE_E = TROWS * TCOLS;  // 348
constexpr int NT2 = 256;               // threads per channel-half
constexpr int NT = 2 * NT2;            // 512
constexpr int NPX = TH * WS;           // 224 compute threads per half
constexpr int EXTRA = TILE_E - NT2;    // 92 threads own a 2nd staging slot
constexpr int CHALF = C_ / 2;          // 96 channels per half
constexpr int KCH = 8;                 // channels per chunk (per half)
constexpr int GRP = KCH / 4;           // 2 float4 groups
constexpr int NCHUNK = CHALF / KCH;    // 12 chunks -> 12 barriers (R6: 24)
constexpr int NBLK = (W_ / WS) * (H_ / TH) * N_;  // 2*28*8 = 448
constexpr float INV_T = 10.0f;
constexpr double TOTAL = (double)N_ * N_ * H_ * W_;  // 802816
}

typedef float v2f __attribute__((ext_vector_type(2)));
typedef float v4f __attribute__((ext_vector_type(4)));

__device__ __forceinline__ void pkfma(v2f& a, v2f x, v2f y) {
    asm("v_pk_fma_f32 %0, %1, %2, %0" : "+v"(a) : "v"(x), "v"(y));
}

__device__ __forceinline__ float sel3(int d, float a, float b, float c) {
    float r = (d < 0) ? a : b;
    return (d > 0) ? c : r;
}

extern "C" __global__ void __launch_bounds__(NT, 4)
dcl_main(const float* __restrict__ feat,
         const int* __restrict__ labels,
         const int* __restrict__ dirs,
         double* __restrict__ partial, int use_partial)
{
    __shared__ v4f   tiles[2][2][GRP][TILE_E];  // [half][dbuf][grp] = 44.5 KB
    __shared__ float ssp[2][TILE_E];            // per-half norm partials, 2.8 KB
    __shared__ float ssbuf[TILE_E];             // combined inv-norms, 1.4 KB
    __shared__ float scomb[NPX][9];             // half1 dot partials (pad->9), 8.1 KB
    __shared__ float red[NT / 64];

    const int tid  = threadIdx.x;
    const int half = tid >> 8;          // channel half: 0 or 1
    const int t8   = tid & (NT2 - 1);   // index within half
    const int gx0 = blockIdx.x * WS;
    const int gy0 = blockIdx.y * TH;
    const int n   = blockIdx.z;

    // ---- staging slot -> clamped global offset
    int gofs0, gofs1 = 0;
    {
        int r = t8 / TCOLS, c = t8 - r * TCOLS;
        gofs0 = min(max(gy0 + r - 1, 0), H_ - 1) * W_ + min(max(gx0 + c - 1, 0), W_ - 1);
        if (t8 < EXTRA) {
            int t2 = t8 + NT2;
            r = t2 / TCOLS; c = t2 - r * TCOLS;
            gofs1 = min(max(gy0 + r - 1, 0), H_ - 1) * W_ + min(max(gx0 + c - 1, 0), W_ - 1);
        }
    }

    const bool is_px = (t8 < NPX);
    const int ty = t8 / WS;               // 0..3
    const int tx = t8 - ty * WS;          // 0..55
    const int gi = gy0 + ty;
    const int gj = gx0 + tx;
    const int ci = (ty + 1) * TCOLS + (tx + 1);

    const float* __restrict__ plane =
        feat + ((size_t)n * C_ + (size_t)half * CHALF) * HW;

    float ss0 = 0.0f, ss1 = 0.0f;

    // ---- prologue: stage chunk 0 into buffer 0
    {
        #pragma unroll
        for (int g = 0; g < GRP; ++g) {
            float a0 = plane[(size_t)(4 * g + 0) * HW + gofs0];
            float a1 = plane[(size_t)(4 * g + 1) * HW + gofs0];
            float a2 = plane[(size_t)(4 * g + 2) * HW + gofs0];
            float a3 = plane[(size_t)(4 * g + 3) * HW + gofs0];
            ss0 += a0 * a0 + a1 * a1 + a2 * a2 + a3 * a3;
            v4f v = {a0, a1, a2, a3};
            tiles[half][0][g][t8] = v;
        }
        if (t8 < EXTRA) {
            #pragma unroll
            for (int g = 0; g < GRP; ++g) {
                float a0 = plane[(size_t)(4 * g + 0) * HW + gofs1];
                float a1 = plane[(size_t)(4 * g + 1) * HW + gofs1];
                float a2 = plane[(size_t)(4 * g + 2) * HW + gofs1];
                float a3 = plane[(size_t)(4 * g + 3) * HW + gofs1];
                ss1 += a0 * a0 + a1 * a1 + a2 * a2 + a3 * a3;
                v4f v = {a0, a1, a2, a3};
                tiles[half][0][g][t8 + NT2] = v;
            }
        }
    }
    __syncthreads();

    v2f s2[9];
    const v2f zero2 = {0.0f, 0.0f};
    #pragma unroll
    for (int d = 0; d < 9; ++d) s2[d] = zero2;

    // ---- chunk loop: 1 barrier per 8 channels per half, double-buffered
    for (int t = 0; t < NCHUNK; ++t) {
        float pv0[KCH], pv1[KCH];
        const bool more = (t + 1 < NCHUNK);
        if (more) {
            const float* p = plane + (size_t)(t + 1) * KCH * HW;
            #pragma unroll
            for (int k = 0; k < KCH; ++k) pv0[k] = p[(size_t)k * HW + gofs0];
            if (t8 < EXTRA) {
                #pragma unroll
                for (int k = 0; k < KCH; ++k) pv1[k] = p[(size_t)k * HW + gofs1];
            }
        }

        if (is_px) {
            #pragma unroll
            for (int g = 0; g < GRP; ++g) {
                const v4f* __restrict__ cp = tiles[half][t & 1][g];
                v4f fc  = cp[ci];
                v4f n00 = cp[ci - TCOLS - 1];
                v4f n01 = cp[ci - TCOLS];
                v4f n02 = cp[ci - TCOLS + 1];
                v4f n10 = cp[ci - 1];
                v4f n12 = cp[ci + 1];
                v4f n20 = cp[ci + TCOLS - 1];
                v4f n21 = cp[ci + TCOLS];
                v4f n22 = cp[ci + TCOLS + 1];
                pkfma(s2[0], fc.lo, n00.lo); pkfma(s2[0], fc.hi, n00.hi);
                pkfma(s2[1], fc.lo, n01.lo); pkfma(s2[1], fc.hi, n01.hi);
                pkfma(s2[2], fc.lo, n02.lo); pkfma(s2[2], fc.hi, n02.hi);
                pkfma(s2[3], fc.lo, n10.lo); pkfma(s2[3], fc.hi, n10.hi);
                pkfma(s2[5], fc.lo, n12.lo); pkfma(s2[5], fc.hi, n12.hi);
                pkfma(s2[6], fc.lo, n20.lo); pkfma(s2[6], fc.hi, n20.hi);
                pkfma(s2[7], fc.lo, n21.lo); pkfma(s2[7], fc.hi, n21.hi);
                pkfma(s2[8], fc.lo, n22.lo); pkfma(s2[8], fc.hi, n22.hi);
            }
        }

        if (more) {
            const int nb = (t + 1) & 1;
            #pragma unroll
            for (int g = 0; g < GRP; ++g) {
                float a0 = pv0[4 * g], a1 = pv0[4 * g + 1];
                float a2 = pv0[4 * g + 2], a3 = pv0[4 * g + 3];
                ss0 += a0 * a0 + a1 * a1 + a2 * a2 + a3 * a3;
                v4f v = {a0, a1, a2, a3};
                tiles[half][nb][g][t8] = v;
            }
            if (t8 < EXTRA) {
                #pragma unroll
                for (int g = 0; g < GRP; ++g) {
                    float a0 = pv1[4 * g], a1 = pv1[4 * g + 1];
                    float a2 = pv1[4 * g + 2], a3 = pv1[4 * g + 3];
                    ss1 += a0 * a0 + a1 * a1 + a2 * a2 + a3 * a3;
                    v4f v = {a0, a1, a2, a3};
                    tiles[half][nb][g][t8 + NT2] = v;
                }
            }
            __syncthreads();
        }
    }

    // ---- publish per-half norm partials + half1's dot partials
    ssp[half][t8] = ss0;
    if (t8 < EXTRA) ssp[half][t8 + NT2] = ss1;
    if (half == 1 && is_px) {
        scomb[t8][0] = s2[0].x + s2[0].y;
        scomb[t8][1] = s2[1].x + s2[1].y;
        scomb[t8][2] = s2[2].x + s2[2].y;
        scomb[t8][3] = s2[3].x + s2[3].y;
        scomb[t8][4] = s2[5].x + s2[5].y;
        scomb[t8][5] = s2[6].x + s2[6].y;
        scomb[t8][6] = s2[7].x + s2[7].y;
        scomb[t8][7] = s2[8].x + s2[8].y;
    }
    __syncthreads();
    if (tid < TILE_E)
        ssbuf[tid] = 1.0f / fmaxf(sqrtf(ssp[0][tid] + ssp[1][tid]), 1e-12f);
    __syncthreads();

    float lp = 0.0f;
    if (half == 0 && is_px) {
        const float sA = s2[0].x + s2[0].y + scomb[t8][0];
        const float sB = s2[1].x + s2[1].y + scomb[t8][1];
        const float sC = s2[2].x + s2[2].y + scomb[t8][2];
        const float sD = s2[3].x + s2[3].y + scomb[t8][3];
        const float sE = s2[5].x + s2[5].y + scomb[t8][4];
        const float sF = s2[6].x + s2[6].y + scomb[t8][5];
        const float sG = s2[7].x + s2[7].y + scomb[t8][6];
        const float sH = s2[8].x + s2[8].y + scomb[t8][7];
        const float ssq = ssp[0][ci] + ssp[1][ci];   // center self-dot

        const float invc = ssbuf[ci] * INV_T;
        const float l00 = sA  * invc * ssbuf[ci - TCOLS - 1];
        const float l01 = sB  * invc * ssbuf[ci - TCOLS];
        const float l02 = sC  * invc * ssbuf[ci - TCOLS + 1];
        const float l10 = sD  * invc * ssbuf[ci - 1];
        const float l11 = ssq * invc * ssbuf[ci];
        const float l12 = sE  * invc * ssbuf[ci + 1];
        const float l20 = sF  * invc * ssbuf[ci + TCOLS - 1];
        const float l21 = sG  * invc * ssbuf[ci + TCOLS];
        const float l22 = sH  * invc * ssbuf[ci + TCOLS + 1];

        const int pix = gi * W_ + gj;
        float denom = 0.f, sumlog = 0.f;
        #pragma unroll
        for (int m = 0; m < N_; ++m) {
            int d0 = dirs[((m * 2 + 0) * H_ + gi) * W_ + gj];
            int d1 = dirs[((m * 2 + 1) * H_ + gi) * W_ + gj];
            float q0 = sel3(d1, l00, l01, l02);
            float q1 = sel3(d1, l10, l11, l12);
            float q2 = sel3(d1, l20, l21, l22);
            float lm = sel3(d0, q0, q1, q2);
            int labm = labels[m * HW + pix];
            int labn = labels[n * HW + (gi + d0) * W_ + (gj + d1)];
            bool msk = (labm == labn);
            float e = msk ? __expf(lm) : 0.f;
            denom += e;
            sumlog += msk ? lm : -INFINITY;
        }
        lp = 8.0f * __logf(denom + 1e-6f) - sumlog;
    }

    // ---- block reduction (8 waves)
    #pragma unroll
    for (int off = 32; off > 0; off >>= 1) lp += __shfl_down(lp, off, 64);
    const int wave = tid >> 6, lane = tid & 63;
    if (lane == 0) red[wave] = lp;
    __syncthreads();
    if (tid == 0) {
        float tsum = 0.f;
        #pragma unroll
        for (int w = 0; w < NT / 64; ++w) tsum += red[w];
        const int bid = (blockIdx.z * gridDim.y + blockIdx.y) * gridDim.x + blockIdx.x;
        if (use_partial) partial[bid] = (double)tsum;
        else atomicAdd(partial, (double)tsum);
    }
}

extern "C" __global__ void __launch_bounds__(256)
dcl_final(const double* __restrict__ partial, float* __restrict__ out, int nblk)
{
    const int tid = threadIdx.x;
    double s = 0.0;
    for (int i = tid; i < nblk; i += 256) s += partial[i];
    #pragma unroll
    for (int off = 32; off > 0; off >>= 1) s += __shfl_down(s, off, 64);
    __shared__ double red[4];
    const int lane = tid & 63, wv = tid >> 6;
    if (lane == 0) red[wv] = s;
    __syncthreads();
    if (tid == 0) out[0] = (float)((red[0] + red[1] + red[2] + red[3]) / TOTAL);
}

extern "C" void kernel_launch(void* const* d_in, const int* in_sizes, int n_in,
                              void* d_out, int out_size, void* d_ws, size_t ws_size,
                              hipStream_t stream) {
    const float* feat   = (const float*)d_in[0];
    const int*   labels = (const int*)d_in[1];
    const int*   dirs   = (const int*)d_in[2];
    double* acc = (double*)d_ws;
    float*  out = (float*)d_out;

    const int use_partial = (ws_size >= (size_t)NBLK * sizeof(double)) ? 1 : 0;
    if (!use_partial) hipMemsetAsync(acc, 0, sizeof(double), stream);
    dim3 grid(W_ / WS, H_ / TH, N_);      // (2, 28, 8) = 448 blocks
    dcl_main<<<grid, NT, 0, stream>>>(feat, labels, dirs, acc, use_partial);
    dcl_final<<<1, 256, 0, stream>>>(acc, out, use_partial ? NBLK : 1);
}